// Round 9
// baseline (306.612 us; speedup 1.0000x reference)
//
#include <hip/hip_runtime.h>
#include <hip/hip_bf16.h>
#include <math.h>

#define N_NODES 4096
#define F_INN   256
#define F_OUTT  64
#define HID     64
#define MAXDEG  64

typedef __attribute__((ext_vector_type(8))) short bf16x8;
typedef __attribute__((ext_vector_type(4))) float f32x4;

// Scratch in device globals (no ws_size dependence). Fully rewritten each call.
__device__ int    g_mode;                    // 0 = fp32 inputs, 1 = bf16 inputs
__device__ int    g_anyArr[64];              // per-block detector flags
__device__ float  g_Wh [N_NODES * F_OUTT];
__device__ float  g_s1 [N_NODES];
__device__ float  g_s2 [N_NODES];
__device__ int    g_rev[N_NODES * MAXDEG];
__device__ int    g_perm[N_NODES];
__device__ float4 g_GX [N_NODES * F_OUTT];   // per (node, unit): quad {i,f,g,o}

__device__ __forceinline__ float bf2f(unsigned short u) {
  union { unsigned int i; float f; } v; v.i = ((unsigned int)u) << 16; return v.f;
}
__device__ __forceinline__ unsigned short f2bf(float f) {
  union { __hip_bfloat16 b; unsigned short u; } v; v.b = __float2bfloat16(f); return v.u;
}

__device__ __forceinline__ float bcastf(float v, int l) {
  return __int_as_float(__builtin_amdgcn_readlane(__float_as_int(v), l));
}

__device__ __forceinline__ float sigm(float x) { return 1.f / (1.f + __expf(-x)); }
__device__ __forceinline__ float tanh_fast(float x) { return 1.f - 2.f / (1.f + __expf(2.f * x)); }

__device__ __forceinline__ bf16x8 zfrag() {
  bf16x8 z;
  #pragma unroll
  for (int i = 0; i < 8; i++) z[i] = 0;
  return z;
}

// Truncation-based hi/lo split (cheap: ~4 VALU insts/elem vs ~11 for RNE).
// hi = top 16 bits of f (exact bf16); lo = trunc16(f - hi). Combined
// representation error ~2^-17 |f| — products remain exact in fp32 MFMA accum.
__device__ __forceinline__ void hilo_t(float4 a, float4 b, bf16x8& hi, bf16x8& lo) {
  float v[8] = {a.x, a.y, a.z, a.w, b.x, b.y, b.z, b.w};
  #pragma unroll
  for (int i = 0; i < 8; i++) {
    unsigned int ui = __float_as_uint(v[i]);
    unsigned int hb = ui & 0xFFFF0000u;
    float lof = v[i] - __uint_as_float(hb);
    hi[i] = (short)(ui >> 16);
    lo[i] = (short)(__float_as_uint(lof) >> 16);
  }
}

#define MFMA16(a, b, c) __builtin_amdgcn_mfma_f32_16x16x32_bf16((a), (b), (c), 0, 0, 0)

// D0: parallel dtype detector (fp32 adj words have zero low16; bf16 doesn't).
__global__ __launch_bounds__(256) void k_detect(const unsigned int* __restrict__ aw) {
  __shared__ int any;
  if (threadIdx.x == 0) any = 0;
  __syncthreads();
  const uint4 v = ((const uint4*)aw)[blockIdx.x * 256 + threadIdx.x];
  int loc = (int)((v.x & 0xFFFFu) | (v.y & 0xFFFFu) | (v.z & 0xFFFFu) | (v.w & 0xFFFFu));
  if (loc) atomicOr(&any, 1);
  __syncthreads();
  if (threadIdx.x == 0) g_anyArr[blockIdx.x] = any;
}

// S1: reduce detector flags -> g_mode; counting sort by seq_length descending.
__global__ __launch_bounds__(256) void k_sort(const int* __restrict__ seq) {
  __shared__ int hist[MAXDEG + 1];
  __shared__ int offs[MAXDEG + 1];
  const int tid = threadIdx.x;
  if (tid <= MAXDEG) hist[tid] = 0;
  __syncthreads();
  if (tid == 0) {
    int any = 0;
    for (int b = 0; b < 64; b++) any |= g_anyArr[b];
    g_mode = any ? 1 : 0;
  }
  for (int i = tid; i < N_NODES; i += 256)
    atomicAdd(&hist[min(max(seq[i], 0), MAXDEG)], 1);
  __syncthreads();
  if (tid == 0) {
    int run = 0;
    for (int L = MAXDEG; L >= 0; L--) { offs[L] = run; run += hist[L]; }
  }
  __syncthreads();
  for (int i = tid; i < N_NODES; i += 256) {
    int p = atomicAdd(&offs[min(max(seq[i], 0), MAXDEG)], 1);
    g_perm[p] = i;
  }
}

// K1: Wh = h @ W (fp64 acc), s1/s2 fp64 dots. Unchanged (proven).
__global__ __launch_bounds__(256) void k_wh(
    const void* __restrict__ h, const void* __restrict__ W, const void* __restrict__ a)
{
  const bool bf16 = (g_mode == 1);
  __shared__ float Ws[F_INN * F_OUTT];   // 64 KB
  const int tid = threadIdx.x;
  if (bf16) {
    const ushort4* Wu = (const ushort4*)W;
    for (int v = tid; v < F_INN * F_OUTT / 4; v += 256) {
      ushort4 u = Wu[v];
      ((float4*)Ws)[v] = make_float4(bf2f(u.x), bf2f(u.y), bf2f(u.z), bf2f(u.w));
    }
  } else {
    const float4* Wf = (const float4*)W;
    for (int v = tid; v < F_INN * F_OUTT / 4; v += 256) ((float4*)Ws)[v] = Wf[v];
  }
  __syncthreads();
  const int wave = tid >> 6, lane = tid & 63;
  const int row = blockIdx.x * 4 + wave;
  float hr0, hr1, hr2, hr3;
  if (bf16) {
    ushort4 v = ((const ushort4*)((const unsigned short*)h + row * F_INN))[lane];
    hr0 = bf2f(v.x); hr1 = bf2f(v.y); hr2 = bf2f(v.z); hr3 = bf2f(v.w);
  } else {
    float4 v = ((const float4*)((const float*)h + row * F_INN))[lane];
    hr0 = v.x; hr1 = v.y; hr2 = v.z; hr3 = v.w;
  }
  double acc = 0.0;
  #pragma unroll 8
  for (int l = 0; l < 64; l++) {
    float h0 = bcastf(hr0, l), h1 = bcastf(hr1, l);
    float h2 = bcastf(hr2, l), h3 = bcastf(hr3, l);
    acc += (double)h0 * (double)Ws[(l * 4 + 0) * F_OUTT + lane];
    acc += (double)h1 * (double)Ws[(l * 4 + 1) * F_OUTT + lane];
    acc += (double)h2 * (double)Ws[(l * 4 + 2) * F_OUTT + lane];
    acc += (double)h3 * (double)Ws[(l * 4 + 3) * F_OUTT + lane];
  }
  const float whv = (float)acc;
  g_Wh[row * F_OUTT + lane] = whv;
  float a1, a2;
  if (bf16) {
    a1 = bf2f(((const unsigned short*)a)[lane]);
    a2 = bf2f(((const unsigned short*)a)[F_OUTT + lane]);
  } else {
    a1 = ((const float*)a)[lane];
    a2 = ((const float*)a)[F_OUTT + lane];
  }
  double t1 = (double)whv * (double)a1;
  double t2 = (double)whv * (double)a2;
  #pragma unroll
  for (int off = 32; off > 0; off >>= 1) {
    t1 += __shfl_down(t1, off);
    t2 += __shfl_down(t2, off);
  }
  if (lane == 0) { g_s1[row] = (float)t1; g_s2[row] = (float)t2; }
}

// K2: attention + fused GX. Byte-identical to round 8.
__global__ __launch_bounds__(256) void k_att(
    const void* __restrict__ adj, const void* __restrict__ w_ih)
{
  const bool bf16 = (g_mode == 1);
  const int i = blockIdx.x, tid = threadIdx.x;
  __shared__ int    nbr[MAXDEG];
  __shared__ float  att_s[MAXDEG];
  __shared__ int    sorted_j[MAXDEG];
  __shared__ double part[4][F_OUTT];
  __shared__ float  wh2row[F_OUTT];
  __shared__ int    cnt;
  if (tid == 0) cnt = 0;
  __syncthreads();
  if (bf16) {
    const uint4* ar = (const uint4*)((const unsigned short*)adj + (size_t)i * N_NODES);
    for (int c = tid; c < N_NODES / 8; c += 256) {
      uint4 v = ar[c];
      unsigned int w[4] = {v.x, v.y, v.z, v.w};
      #pragma unroll
      for (int k = 0; k < 4; k++) {
        if (w[k] & 0x0000FFFFu) { int p = atomicAdd(&cnt, 1); if (p < MAXDEG) nbr[p] = c*8 + k*2; }
        if (w[k] & 0xFFFF0000u) { int p = atomicAdd(&cnt, 1); if (p < MAXDEG) nbr[p] = c*8 + k*2 + 1; }
      }
    }
  } else {
    const float4* ar = (const float4*)((const float*)adj + (size_t)i * N_NODES);
    for (int c = tid; c < N_NODES / 4; c += 256) {
      float4 v = ar[c];
      if (v.x != 0.0f) { int p = atomicAdd(&cnt, 1); if (p < MAXDEG) nbr[p] = c*4;     }
      if (v.y != 0.0f) { int p = atomicAdd(&cnt, 1); if (p < MAXDEG) nbr[p] = c*4 + 1; }
      if (v.z != 0.0f) { int p = atomicAdd(&cnt, 1); if (p < MAXDEG) nbr[p] = c*4 + 2; }
      if (v.w != 0.0f) { int p = atomicAdd(&cnt, 1); if (p < MAXDEG) nbr[p] = c*4 + 3; }
    }
  }
  __syncthreads();
  const int L = min(cnt, MAXDEG);
  float ef = -3.0e38f; int jn = 0x7fffffff;
  if (tid < L) {
    jn = nbr[tid];
    float s = g_s1[i] + g_s2[jn];
    ef = (s > 0.0f) ? s : 0.2f * s;
  }
  float af = 0.0f;
  if (tid < 64) {
    float m = ef;
    #pragma unroll
    for (int off = 32; off > 0; off >>= 1) m = fmaxf(m, __shfl_down(m, off));
    m = __shfl(m, 0);
    double p = (tid < L) ? exp((double)(ef - m)) : 0.0;
    double ssum = p;
    #pragma unroll
    for (int off = 32; off > 0; off >>= 1) ssum += __shfl_down(ssum, off);
    ssum = __shfl(ssum, 0);
    af = (float)(p / ssum);
    att_s[tid] = af;
  }
  __syncthreads();
  if (tid < L) {
    int rank = 0;
    for (int q = 0; q < L; q++) {
      float aq = att_s[q]; int jq = nbr[q];
      if (aq > af || (aq == af && jq < jn)) rank++;
    }
    sorted_j[rank] = jn;
  }
  {
    const int wave = tid >> 6, lane = tid & 63;
    double acc = 0.0;
    for (int q = wave; q < L; q += 4)
      acc += (double)att_s[q] * (double)g_Wh[(size_t)nbr[q] * F_OUTT + lane];
    part[wave][lane] = acc;
  }
  __syncthreads();
  if (tid < MAXDEG)
    g_rev[i * MAXDEG + tid] = (tid < L) ? sorted_j[L - 1 - tid] : 0;
  if (tid < 64)
    wh2row[tid] = (float)(part[0][tid] + part[1][tid] + part[2][tid] + part[3][tid]);
  __syncthreads();
  {
    double acc = 0.0;
    if (bf16) {
      const uint2* wrow = (const uint2*)((const unsigned short*)w_ih + (size_t)tid * F_OUTT);
      #pragma unroll
      for (int q = 0; q < 16; q++) {
        uint2 v = wrow[q];
        acc += (double)bf2f((unsigned short)(v.x & 0xFFFFu)) * (double)wh2row[q*4 + 0];
        acc += (double)bf2f((unsigned short)(v.x >> 16))     * (double)wh2row[q*4 + 1];
        acc += (double)bf2f((unsigned short)(v.y & 0xFFFFu)) * (double)wh2row[q*4 + 2];
        acc += (double)bf2f((unsigned short)(v.y >> 16))     * (double)wh2row[q*4 + 3];
      }
    } else {
      const float4* wrow = (const float4*)((const float*)w_ih + (size_t)tid * F_OUTT);
      #pragma unroll
      for (int q = 0; q < 16; q++) {
        float4 v = wrow[q];
        acc += (double)v.x * (double)wh2row[q*4 + 0];
        acc += (double)v.y * (double)wh2row[q*4 + 1];
        acc += (double)v.z * (double)wh2row[q*4 + 2];
        acc += (double)v.w * (double)wh2row[q*4 + 3];
      }
    }
    ((float*)g_GX)[(i * F_OUTT + (tid & 63)) * 4 + (tid >> 6)] = (float)acc;
  }
}

// K4-MFMA v5: DUAL-GROUP blocks — 32 sorted rows/block, 512 threads, grid 128.
// Waves 0-3 run rows rb..rb+15 (group 0), waves 4-7 rows rb+16..rb+31
// (group 1). Each SIMD hosts one wave from each group: one group's
// MFMA-issue / LDS / dependency stalls are filled by the other group's
// instructions — this shortens the critical (longest-L) block's wall clock,
// which sets kernel duration (r8 analysis: wall = 64 x per-step chain).
// In-loop h split uses the cheap truncation hilo_t. Math otherwise as r8.
__global__ __launch_bounds__(512, 1) void k_lstm_mfma(
    const void* __restrict__ w_hh, const void* __restrict__ b_ih,
    const void* __restrict__ b_hh, const int* __restrict__ seq,
    void* __restrict__ out)
{
  const bool bf16 = (g_mode == 1);
  __shared__ __align__(16) float lds_h[2][2][16 * 68];
  const int tid = threadIdx.x;
  const int grp = tid >> 8;            // 0 or 1
  const int w = (tid >> 6) & 3, lane = tid & 63;
  const int q = lane >> 4, c = lane & 15;
  const int rb = blockIdx.x * 32 + grp * 16;

  // Block-wide loop bound: first row of the block is the longest (sorted).
  const int Lmax = min(max(seq[g_perm[blockIdx.x * 32] & (N_NODES - 1)], 0), MAXDEG);
  int row_e[4], Ls_e[4], rvb[4];
  #pragma unroll
  for (int r = 0; r < 4; r++) {
    row_e[r] = g_perm[rb + q * 4 + r] & (N_NODES - 1);
    Ls_e[r]  = min(max(seq[row_e[r]], 0), MAXDEG);
    rvb[r]   = row_e[r] * MAXDEG;
  }
  const int d_unit = 16 * w + c;   // unit index 0..63 handled by this lane

  // B fragments (loaded once): col = unit 64g + 16w + c, k-chunk ch.
  bf16x8 Bhi[4][2], Blo[4][2];
  float bs[4];
  #pragma unroll
  for (int g = 0; g < 4; g++) {
    const int col = 64 * g + d_unit;
    #pragma unroll
    for (int ch = 0; ch < 2; ch++) {
      if (bf16) {
        Bhi[g][ch] = *(const bf16x8*)((const unsigned short*)w_hh + (size_t)col * 64 + ch * 32 + q * 8);
        Blo[g][ch] = zfrag();
      } else {
        const float* wp = (const float*)w_hh + (size_t)col * 64 + ch * 32 + q * 8;
        hilo_t(*(const float4*)wp, *(const float4*)(wp + 4), Bhi[g][ch], Blo[g][ch]);
      }
    }
    bs[g] = bf16
      ? bf2f(((const unsigned short*)b_ih)[col]) + bf2f(((const unsigned short*)b_hh)[col])
      : ((const float*)b_ih)[col] + ((const float*)b_hh)[col];
  }

  // gx pipeline: gxq = step t's quads; src_n = node for step t+1.
  float4 gxq[4];
  int src_n[4];
  #pragma unroll
  for (int r = 0; r < 4; r++) {
    int s0 = g_rev[rvb[r]] & (N_NODES - 1);
    gxq[r]  = g_GX[s0 * F_OUTT + d_unit];
    src_n[r] = g_rev[rvb[r] + 1] & (N_NODES - 1);
  }

  bf16x8 hh0 = zfrag(), hh1 = zfrag(), hl0 = zfrag(), hl1 = zfrag();
  float cst[4] = {0.f, 0.f, 0.f, 0.f}, hst[4] = {0.f, 0.f, 0.f, 0.f};

  for (int t = 0; t < Lmax; t++) {
    // prefetch: indices for t+2, gx quads for t+1 (src_n already resident)
    int src_n2[4];
    float4 ngx[4];
    #pragma unroll
    for (int r = 0; r < 4; r++) {
      src_n2[r] = g_rev[rvb[r] + min(t + 2, MAXDEG - 1)] & (N_NODES - 1);
      ngx[r]    = g_GX[src_n[r] * F_OUTT + d_unit];
    }
    float gxa[4][4];
    #pragma unroll
    for (int r = 0; r < 4; r++) {
      gxa[0][r] = gxq[r].x; gxa[1][r] = gxq[r].y;
      gxa[2][r] = gxq[r].z; gxa[3][r] = gxq[r].w;
    }
    f32x4 acc[4];
    #pragma unroll
    for (int g = 0; g < 4; g++) {
      f32x4 a;
      a[0] = bs[g] + gxa[g][0]; a[1] = bs[g] + gxa[g][1];
      a[2] = bs[g] + gxa[g][2]; a[3] = bs[g] + gxa[g][3];
      a = MFMA16(hh0, Bhi[g][0], a);
      a = MFMA16(hh1, Bhi[g][1], a);
      a = MFMA16(hl0, Bhi[g][0], a);
      a = MFMA16(hl1, Bhi[g][1], a);
      a = MFMA16(hh0, Blo[g][0], a);
      a = MFMA16(hh1, Blo[g][1], a);
      acc[g] = a;
    }
    float* lh = lds_h[grp][t & 1];
    #pragma unroll
    for (int r = 0; r < 4; r++) {
      float ig = sigm(acc[0][r]);
      float fg = sigm(acc[1][r]);
      float gg = tanh_fast(acc[2][r]);
      float og = sigm(acc[3][r]);
      float cn = fg * cst[r] + ig * gg;
      float hn = og * tanh_fast(cn);
      bool live = (t < Ls_e[r]);
      cst[r] = live ? cn : cst[r];
      hst[r] = live ? hn : hst[r];
      lh[(q * 4 + r) * 68 + d_unit] = hst[r];
    }
    __syncthreads();
    // rebuild h A-fragments: lane (q,c) -> A[m=c][k=ch*32+8q+j]
    float4 v0 = *(const float4*)&lh[c * 68 + 8 * q];
    float4 v1 = *(const float4*)&lh[c * 68 + 8 * q + 4];
    float4 v2 = *(const float4*)&lh[c * 68 + 32 + 8 * q];
    float4 v3 = *(const float4*)&lh[c * 68 + 32 + 8 * q + 4];
    hilo_t(v0, v1, hh0, hl0);
    hilo_t(v2, v3, hh1, hl1);
    #pragma unroll
    for (int r = 0; r < 4; r++) { gxq[r] = ngx[r]; src_n[r] = src_n2[r]; }
  }
  #pragma unroll
  for (int r = 0; r < 4; r++) {
    if (bf16) ((__hip_bfloat16*)out)[row_e[r] * HID + d_unit] = __float2bfloat16(hst[r]);
    else      ((float*)out)[row_e[r] * HID + d_unit] = hst[r];
  }
}

extern "C" void kernel_launch(void* const* d_in, const int* in_sizes, int n_in,
                              void* d_out, int out_size, void* d_ws, size_t ws_size,
                              hipStream_t stream) {
  (void)in_sizes; (void)n_in; (void)out_size; (void)d_ws; (void)ws_size;
  const void* h    = d_in[0];
  const void* adj  = d_in[1];
  const int*  seq  = (const int*)d_in[2];
  const void* W    = d_in[3];
  const void* a    = d_in[4];
  const void* w_ih = d_in[5];
  const void* w_hh = d_in[6];
  const void* b_ih = d_in[7];
  const void* b_hh = d_in[8];

  k_detect   <<<64,           256, 0, stream>>>((const unsigned int*)adj);
  k_sort     <<<1,            256, 0, stream>>>(seq);
  k_wh       <<<N_NODES / 4,  256, 0, stream>>>(h, W, a);
  k_att      <<<N_NODES,      256, 0, stream>>>(adj, w_ih);
  k_lstm_mfma<<<N_NODES / 32, 512, 0, stream>>>(w_hh, b_ih, b_hh, seq, d_out);
}

// Round 10
// 265.679 us; speedup vs baseline: 1.1541x; 1.1541x over previous
//
#include <hip/hip_runtime.h>
#include <hip/hip_bf16.h>
#include <math.h>

#define N_NODES 4096
#define F_INN   256
#define F_OUTT  64
#define HID     64
#define MAXDEG  64

typedef __attribute__((ext_vector_type(8))) short bf16x8;
typedef __attribute__((ext_vector_type(4))) float f32x4;

// Scratch in device globals (no ws_size dependence). Fully rewritten each call.
__device__ int    g_mode;                    // 0 = fp32 inputs, 1 = bf16 inputs
__device__ int    g_anyArr[64];              // per-block detector flags
__device__ float  g_Wh [N_NODES * F_OUTT];
__device__ float  g_s1 [N_NODES];
__device__ float  g_s2 [N_NODES];
__device__ int    g_rev[N_NODES * MAXDEG];
__device__ int    g_perm[N_NODES];
__device__ float4 g_GX [N_NODES * F_OUTT];   // per (node, unit): quad {i,f,g,o}

__device__ __forceinline__ float bf2f(unsigned short u) {
  union { unsigned int i; float f; } v; v.i = ((unsigned int)u) << 16; return v.f;
}
__device__ __forceinline__ unsigned short f2bf(float f) {
  union { __hip_bfloat16 b; unsigned short u; } v; v.b = __float2bfloat16(f); return v.u;
}

__device__ __forceinline__ float bcastf(float v, int l) {
  return __int_as_float(__builtin_amdgcn_readlane(__float_as_int(v), l));
}

__device__ __forceinline__ float sigm(float x) { return 1.f / (1.f + __expf(-x)); }
__device__ __forceinline__ float tanh_fast(float x) { return 1.f - 2.f / (1.f + __expf(2.f * x)); }

__device__ __forceinline__ bf16x8 zfrag() {
  bf16x8 z;
  #pragma unroll
  for (int i = 0; i < 8; i++) z[i] = 0;
  return z;
}

// Truncation-based hi/lo split (cheap: ~4 VALU insts/elem vs ~11 for RNE).
__device__ __forceinline__ void hilo_t(float4 a, float4 b, bf16x8& hi, bf16x8& lo) {
  float v[8] = {a.x, a.y, a.z, a.w, b.x, b.y, b.z, b.w};
  #pragma unroll
  for (int i = 0; i < 8; i++) {
    unsigned int ui = __float_as_uint(v[i]);
    unsigned int hb = ui & 0xFFFF0000u;
    float lof = v[i] - __uint_as_float(hb);
    hi[i] = (short)(ui >> 16);
    lo[i] = (short)(__float_as_uint(lof) >> 16);
  }
}

// Lightweight block barrier for LDS-only exchange: orders ds ops
// (lgkmcnt(0)) but does NOT drain vmcnt — in-flight global prefetches
// survive the barrier (their consumption is data-ordered at use point).
// __syncthreads() would emit s_waitcnt vmcnt(0) and serialize the gx
// gather latency into every step (the m97 barrier-drain pathology).
__device__ __forceinline__ void block_sync_lds() {
  __asm__ volatile("s_waitcnt lgkmcnt(0)" ::: "memory");
  __builtin_amdgcn_s_barrier();
}

#define MFMA16(a, b, c) __builtin_amdgcn_mfma_f32_16x16x32_bf16((a), (b), (c), 0, 0, 0)

// D0: parallel dtype detector (fp32 adj words have zero low16; bf16 doesn't).
__global__ __launch_bounds__(256) void k_detect(const unsigned int* __restrict__ aw) {
  __shared__ int any;
  if (threadIdx.x == 0) any = 0;
  __syncthreads();
  const uint4 v = ((const uint4*)aw)[blockIdx.x * 256 + threadIdx.x];
  int loc = (int)((v.x & 0xFFFFu) | (v.y & 0xFFFFu) | (v.z & 0xFFFFu) | (v.w & 0xFFFFu));
  if (loc) atomicOr(&any, 1);
  __syncthreads();
  if (threadIdx.x == 0) g_anyArr[blockIdx.x] = any;
}

// S1: reduce detector flags -> g_mode; counting sort by seq_length descending.
__global__ __launch_bounds__(256) void k_sort(const int* __restrict__ seq) {
  __shared__ int hist[MAXDEG + 1];
  __shared__ int offs[MAXDEG + 1];
  const int tid = threadIdx.x;
  if (tid <= MAXDEG) hist[tid] = 0;
  __syncthreads();
  if (tid == 0) {
    int any = 0;
    for (int b = 0; b < 64; b++) any |= g_anyArr[b];
    g_mode = any ? 1 : 0;
  }
  for (int i = tid; i < N_NODES; i += 256)
    atomicAdd(&hist[min(max(seq[i], 0), MAXDEG)], 1);
  __syncthreads();
  if (tid == 0) {
    int run = 0;
    for (int L = MAXDEG; L >= 0; L--) { offs[L] = run; run += hist[L]; }
  }
  __syncthreads();
  for (int i = tid; i < N_NODES; i += 256) {
    int p = atomicAdd(&offs[min(max(seq[i], 0), MAXDEG)], 1);
    g_perm[p] = i;
  }
}

// K1: Wh = h @ W (fp64 acc), s1/s2 fp64 dots. Unchanged (proven).
__global__ __launch_bounds__(256) void k_wh(
    const void* __restrict__ h, const void* __restrict__ W, const void* __restrict__ a)
{
  const bool bf16 = (g_mode == 1);
  __shared__ float Ws[F_INN * F_OUTT];   // 64 KB
  const int tid = threadIdx.x;
  if (bf16) {
    const ushort4* Wu = (const ushort4*)W;
    for (int v = tid; v < F_INN * F_OUTT / 4; v += 256) {
      ushort4 u = Wu[v];
      ((float4*)Ws)[v] = make_float4(bf2f(u.x), bf2f(u.y), bf2f(u.z), bf2f(u.w));
    }
  } else {
    const float4* Wf = (const float4*)W;
    for (int v = tid; v < F_INN * F_OUTT / 4; v += 256) ((float4*)Ws)[v] = Wf[v];
  }
  __syncthreads();
  const int wave = tid >> 6, lane = tid & 63;
  const int row = blockIdx.x * 4 + wave;
  float hr0, hr1, hr2, hr3;
  if (bf16) {
    ushort4 v = ((const ushort4*)((const unsigned short*)h + row * F_INN))[lane];
    hr0 = bf2f(v.x); hr1 = bf2f(v.y); hr2 = bf2f(v.z); hr3 = bf2f(v.w);
  } else {
    float4 v = ((const float4*)((const float*)h + row * F_INN))[lane];
    hr0 = v.x; hr1 = v.y; hr2 = v.z; hr3 = v.w;
  }
  double acc = 0.0;
  #pragma unroll 8
  for (int l = 0; l < 64; l++) {
    float h0 = bcastf(hr0, l), h1 = bcastf(hr1, l);
    float h2 = bcastf(hr2, l), h3 = bcastf(hr3, l);
    acc += (double)h0 * (double)Ws[(l * 4 + 0) * F_OUTT + lane];
    acc += (double)h1 * (double)Ws[(l * 4 + 1) * F_OUTT + lane];
    acc += (double)h2 * (double)Ws[(l * 4 + 2) * F_OUTT + lane];
    acc += (double)h3 * (double)Ws[(l * 4 + 3) * F_OUTT + lane];
  }
  const float whv = (float)acc;
  g_Wh[row * F_OUTT + lane] = whv;
  float a1, a2;
  if (bf16) {
    a1 = bf2f(((const unsigned short*)a)[lane]);
    a2 = bf2f(((const unsigned short*)a)[F_OUTT + lane]);
  } else {
    a1 = ((const float*)a)[lane];
    a2 = ((const float*)a)[F_OUTT + lane];
  }
  double t1 = (double)whv * (double)a1;
  double t2 = (double)whv * (double)a2;
  #pragma unroll
  for (int off = 32; off > 0; off >>= 1) {
    t1 += __shfl_down(t1, off);
    t2 += __shfl_down(t2, off);
  }
  if (lane == 0) { g_s1[row] = (float)t1; g_s2[row] = (float)t2; }
}

// K2: attention + fused GX. Byte-identical to rounds 8/9.
__global__ __launch_bounds__(256) void k_att(
    const void* __restrict__ adj, const void* __restrict__ w_ih)
{
  const bool bf16 = (g_mode == 1);
  const int i = blockIdx.x, tid = threadIdx.x;
  __shared__ int    nbr[MAXDEG];
  __shared__ float  att_s[MAXDEG];
  __shared__ int    sorted_j[MAXDEG];
  __shared__ double part[4][F_OUTT];
  __shared__ float  wh2row[F_OUTT];
  __shared__ int    cnt;
  if (tid == 0) cnt = 0;
  __syncthreads();
  if (bf16) {
    const uint4* ar = (const uint4*)((const unsigned short*)adj + (size_t)i * N_NODES);
    for (int c = tid; c < N_NODES / 8; c += 256) {
      uint4 v = ar[c];
      unsigned int w[4] = {v.x, v.y, v.z, v.w};
      #pragma unroll
      for (int k = 0; k < 4; k++) {
        if (w[k] & 0x0000FFFFu) { int p = atomicAdd(&cnt, 1); if (p < MAXDEG) nbr[p] = c*8 + k*2; }
        if (w[k] & 0xFFFF0000u) { int p = atomicAdd(&cnt, 1); if (p < MAXDEG) nbr[p] = c*8 + k*2 + 1; }
      }
    }
  } else {
    const float4* ar = (const float4*)((const float*)adj + (size_t)i * N_NODES);
    for (int c = tid; c < N_NODES / 4; c += 256) {
      float4 v = ar[c];
      if (v.x != 0.0f) { int p = atomicAdd(&cnt, 1); if (p < MAXDEG) nbr[p] = c*4;     }
      if (v.y != 0.0f) { int p = atomicAdd(&cnt, 1); if (p < MAXDEG) nbr[p] = c*4 + 1; }
      if (v.z != 0.0f) { int p = atomicAdd(&cnt, 1); if (p < MAXDEG) nbr[p] = c*4 + 2; }
      if (v.w != 0.0f) { int p = atomicAdd(&cnt, 1); if (p < MAXDEG) nbr[p] = c*4 + 3; }
    }
  }
  __syncthreads();
  const int L = min(cnt, MAXDEG);
  float ef = -3.0e38f; int jn = 0x7fffffff;
  if (tid < L) {
    jn = nbr[tid];
    float s = g_s1[i] + g_s2[jn];
    ef = (s > 0.0f) ? s : 0.2f * s;
  }
  float af = 0.0f;
  if (tid < 64) {
    float m = ef;
    #pragma unroll
    for (int off = 32; off > 0; off >>= 1) m = fmaxf(m, __shfl_down(m, off));
    m = __shfl(m, 0);
    double p = (tid < L) ? exp((double)(ef - m)) : 0.0;
    double ssum = p;
    #pragma unroll
    for (int off = 32; off > 0; off >>= 1) ssum += __shfl_down(ssum, off);
    ssum = __shfl(ssum, 0);
    af = (float)(p / ssum);
    att_s[tid] = af;
  }
  __syncthreads();
  if (tid < L) {
    int rank = 0;
    for (int q = 0; q < L; q++) {
      float aq = att_s[q]; int jq = nbr[q];
      if (aq > af || (aq == af && jq < jn)) rank++;
    }
    sorted_j[rank] = jn;
  }
  {
    const int wave = tid >> 6, lane = tid & 63;
    double acc = 0.0;
    for (int q = wave; q < L; q += 4)
      acc += (double)att_s[q] * (double)g_Wh[(size_t)nbr[q] * F_OUTT + lane];
    part[wave][lane] = acc;
  }
  __syncthreads();
  if (tid < MAXDEG)
    g_rev[i * MAXDEG + tid] = (tid < L) ? sorted_j[L - 1 - tid] : 0;
  if (tid < 64)
    wh2row[tid] = (float)(part[0][tid] + part[1][tid] + part[2][tid] + part[3][tid]);
  __syncthreads();
  {
    double acc = 0.0;
    if (bf16) {
      const uint2* wrow = (const uint2*)((const unsigned short*)w_ih + (size_t)tid * F_OUTT);
      #pragma unroll
      for (int q = 0; q < 16; q++) {
        uint2 v = wrow[q];
        acc += (double)bf2f((unsigned short)(v.x & 0xFFFFu)) * (double)wh2row[q*4 + 0];
        acc += (double)bf2f((unsigned short)(v.x >> 16))     * (double)wh2row[q*4 + 1];
        acc += (double)bf2f((unsigned short)(v.y & 0xFFFFu)) * (double)wh2row[q*4 + 2];
        acc += (double)bf2f((unsigned short)(v.y >> 16))     * (double)wh2row[q*4 + 3];
      }
    } else {
      const float4* wrow = (const float4*)((const float*)w_ih + (size_t)tid * F_OUTT);
      #pragma unroll
      for (int q = 0; q < 16; q++) {
        float4 v = wrow[q];
        acc += (double)v.x * (double)wh2row[q*4 + 0];
        acc += (double)v.y * (double)wh2row[q*4 + 1];
        acc += (double)v.z * (double)wh2row[q*4 + 2];
        acc += (double)v.w * (double)wh2row[q*4 + 3];
      }
    }
    ((float*)g_GX)[(i * F_OUTT + (tid & 63)) * 4 + (tid >> 6)] = (float)acc;
  }
}

// K4-MFMA v6: r8 shape (16 rows, 256 threads, grid 256 — proven 89 µs) plus:
// (a) lightweight barrier (lgkm-only; no vmcnt drain) so gx gathers stay in
//     flight across the per-step barrier; (b) 2-step-deep gx pipeline
//     (use t / in-flight t+1 / issue t+2) so the vmcnt wait at use always
//     has >= 2 steps of slack; (c) cheap truncation hilo_t (r9-validated).
// Per-row math identical to r8/r9.
__global__ __launch_bounds__(256, 1) void k_lstm_mfma(
    const void* __restrict__ w_hh, const void* __restrict__ b_ih,
    const void* __restrict__ b_hh, const int* __restrict__ seq,
    void* __restrict__ out)
{
  const bool bf16 = (g_mode == 1);
  __shared__ __align__(16) float lds_h[2][16 * 68];
  const int tid = threadIdx.x;
  const int w = tid >> 6, lane = tid & 63;
  const int q = lane >> 4, c = lane & 15;
  const int rb = blockIdx.x * 16;

  const int Lmax = min(max(seq[g_perm[rb] & (N_NODES - 1)], 0), MAXDEG);
  int row_e[4], Ls_e[4], rvb[4];
  #pragma unroll
  for (int r = 0; r < 4; r++) {
    row_e[r] = g_perm[rb + q * 4 + r] & (N_NODES - 1);
    Ls_e[r]  = min(max(seq[row_e[r]], 0), MAXDEG);
    rvb[r]   = row_e[r] * MAXDEG;
  }
  const int d_unit = 16 * w + c;   // unit index 0..63 handled by this lane

  // B fragments (loaded once): col = unit 64g + 16w + c, k-chunk ch.
  bf16x8 Bhi[4][2], Blo[4][2];
  float bs[4];
  #pragma unroll
  for (int g = 0; g < 4; g++) {
    const int col = 64 * g + d_unit;
    #pragma unroll
    for (int ch = 0; ch < 2; ch++) {
      if (bf16) {
        Bhi[g][ch] = *(const bf16x8*)((const unsigned short*)w_hh + (size_t)col * 64 + ch * 32 + q * 8);
        Blo[g][ch] = zfrag();
      } else {
        const float* wp = (const float*)w_hh + (size_t)col * 64 + ch * 32 + q * 8;
        hilo_t(*(const float4*)wp, *(const float4*)(wp + 4), Bhi[g][ch], Blo[g][ch]);
      }
    }
    bs[g] = bf16
      ? bf2f(((const unsigned short*)b_ih)[col]) + bf2f(((const unsigned short*)b_hh)[col])
      : ((const float*)b_ih)[col] + ((const float*)b_hh)[col];
  }

  // gx pipeline, depth 2: gxq = gx[t], gxn = gx[t+1] (in flight/arrived),
  // src_f = node index for t+2 (resident).
  float4 gxq[4], gxn[4];
  int src_f[4];
  #pragma unroll
  for (int r = 0; r < 4; r++) {
    int s0 = g_rev[rvb[r]] & (N_NODES - 1);
    int s1 = g_rev[rvb[r] + 1] & (N_NODES - 1);
    gxq[r]  = g_GX[s0 * F_OUTT + d_unit];
    gxn[r]  = g_GX[s1 * F_OUTT + d_unit];
    src_f[r] = g_rev[rvb[r] + 2] & (N_NODES - 1);
  }

  bf16x8 hh0 = zfrag(), hh1 = zfrag(), hl0 = zfrag(), hl1 = zfrag();
  float cst[4] = {0.f, 0.f, 0.f, 0.f}, hst[4] = {0.f, 0.f, 0.f, 0.f};

  for (int t = 0; t < Lmax; t++) {
    // issue loads for t+2 (gx) and t+3 (index); consumed 2 steps later
    int src_f2[4];
    float4 gxf[4];
    #pragma unroll
    for (int r = 0; r < 4; r++) {
      gxf[r]    = g_GX[src_f[r] * F_OUTT + d_unit];
      src_f2[r] = g_rev[rvb[r] + min(t + 3, MAXDEG - 1)] & (N_NODES - 1);
    }
    float gxa[4][4];
    #pragma unroll
    for (int r = 0; r < 4; r++) {
      gxa[0][r] = gxq[r].x; gxa[1][r] = gxq[r].y;
      gxa[2][r] = gxq[r].z; gxa[3][r] = gxq[r].w;
    }
    f32x4 acc[4];
    #pragma unroll
    for (int g = 0; g < 4; g++) {
      f32x4 a;
      a[0] = bs[g] + gxa[g][0]; a[1] = bs[g] + gxa[g][1];
      a[2] = bs[g] + gxa[g][2]; a[3] = bs[g] + gxa[g][3];
      a = MFMA16(hh0, Bhi[g][0], a);
      a = MFMA16(hh1, Bhi[g][1], a);
      a = MFMA16(hl0, Bhi[g][0], a);
      a = MFMA16(hl1, Bhi[g][1], a);
      a = MFMA16(hh0, Blo[g][0], a);
      a = MFMA16(hh1, Blo[g][1], a);
      acc[g] = a;
    }
    float* lh = lds_h[t & 1];
    #pragma unroll
    for (int r = 0; r < 4; r++) {
      float ig = sigm(acc[0][r]);
      float fg = sigm(acc[1][r]);
      float gg = tanh_fast(acc[2][r]);
      float og = sigm(acc[3][r]);
      float cn = fg * cst[r] + ig * gg;
      float hn = og * tanh_fast(cn);
      bool live = (t < Ls_e[r]);
      cst[r] = live ? cn : cst[r];
      hst[r] = live ? hn : hst[r];
      lh[(q * 4 + r) * 68 + d_unit] = hst[r];
    }
    block_sync_lds();   // lgkm-only barrier: gx prefetches stay in flight
    // rebuild h A-fragments: lane (q,c) -> A[m=c][k=ch*32+8q+j]
    float4 v0 = *(const float4*)&lh[c * 68 + 8 * q];
    float4 v1 = *(const float4*)&lh[c * 68 + 8 * q + 4];
    float4 v2 = *(const float4*)&lh[c * 68 + 32 + 8 * q];
    float4 v3 = *(const float4*)&lh[c * 68 + 32 + 8 * q + 4];
    hilo_t(v0, v1, hh0, hl0);
    hilo_t(v2, v3, hh1, hl1);
    #pragma unroll
    for (int r = 0; r < 4; r++) {
      gxq[r] = gxn[r]; gxn[r] = gxf[r]; src_f[r] = src_f2[r];
    }
  }
  #pragma unroll
  for (int r = 0; r < 4; r++) {
    if (bf16) ((__hip_bfloat16*)out)[row_e[r] * HID + d_unit] = __float2bfloat16(hst[r]);
    else      ((float*)out)[row_e[r] * HID + d_unit] = hst[r];
  }
}

extern "C" void kernel_launch(void* const* d_in, const int* in_sizes, int n_in,
                              void* d_out, int out_size, void* d_ws, size_t ws_size,
                              hipStream_t stream) {
  (void)in_sizes; (void)n_in; (void)out_size; (void)d_ws; (void)ws_size;
  const void* h    = d_in[0];
  const void* adj  = d_in[1];
  const int*  seq  = (const int*)d_in[2];
  const void* W    = d_in[3];
  const void* a    = d_in[4];
  const void* w_ih = d_in[5];
  const void* w_hh = d_in[6];
  const void* b_ih = d_in[7];
  const void* b_hh = d_in[8];

  k_detect   <<<64,           256, 0, stream>>>((const unsigned int*)adj);
  k_sort     <<<1,            256, 0, stream>>>(seq);
  k_wh       <<<N_NODES / 4,  256, 0, stream>>>(h, W, a);
  k_att      <<<N_NODES,      256, 0, stream>>>(adj, w_ih);
  k_lstm_mfma<<<N_NODES / 16, 256, 0, stream>>>(w_hh, b_ih, b_hh, seq, d_out);
}

// Round 11
// 254.172 us; speedup vs baseline: 1.2063x; 1.0453x over previous
//
#include <hip/hip_runtime.h>
#include <hip/hip_bf16.h>
#include <math.h>

#define N_NODES 4096
#define F_INN   256
#define F_OUTT  64
#define HID     64
#define MAXDEG  64

typedef __attribute__((ext_vector_type(8))) short bf16x8;
typedef __attribute__((ext_vector_type(4))) float f32x4;
typedef __attribute__((ext_vector_type(4))) unsigned int u32x4;

// Scratch in device globals (no ws_size dependence). Fully rewritten each call.
__device__ int    g_mode;                    // 0 = fp32 inputs, 1 = bf16 inputs
__device__ int    g_anyArr[64];              // per-block detector flags
__device__ float  g_Wh [N_NODES * F_OUTT];
__device__ float  g_s1 [N_NODES];
__device__ float  g_s2 [N_NODES];
__device__ int    g_rev[N_NODES * MAXDEG];
__device__ int    g_perm[N_NODES];
__device__ float4 g_GX [N_NODES * F_OUTT];   // per (node, unit): quad {i,f,g,o} + bias

__device__ __forceinline__ float bf2f(unsigned short u) {
  union { unsigned int i; float f; } v; v.i = ((unsigned int)u) << 16; return v.f;
}
__device__ __forceinline__ unsigned short f2bf(float f) {   // RNE
  union { __hip_bfloat16 b; unsigned short u; } v; v.b = __float2bfloat16(f); return v.u;
}

__device__ __forceinline__ float bcastf(float v, int l) {
  return __int_as_float(__builtin_amdgcn_readlane(__float_as_int(v), l));
}

__device__ __forceinline__ float sigm(float x) { return 1.f / (1.f + __expf(-x)); }
__device__ __forceinline__ float tanh_fast(float x) { return 1.f - 2.f / (1.f + __expf(2.f * x)); }

__device__ __forceinline__ bf16x8 zfrag() {
  bf16x8 z;
  #pragma unroll
  for (int i = 0; i < 8; i++) z[i] = 0;
  return z;
}

// byte-permute: result = selected bytes of (s0,s1); sel byte 0-3 -> s1, 4-7 -> s0
__device__ __forceinline__ unsigned int permb(unsigned int s0, unsigned int s1, unsigned int sel) {
#if __has_builtin(__builtin_amdgcn_perm)
  return __builtin_amdgcn_perm(s0, s1, sel);
#else
  union { unsigned int w; unsigned char b[4]; } a, b, r;
  a.w = s0; b.w = s1;
  #pragma unroll
  for (int i = 0; i < 4; i++) {
    unsigned int s = (sel >> (8 * i)) & 0xFF;
    r.b[i] = (s < 4) ? b.b[s] : a.b[s - 4];
  }
  return r.w;
#endif
}

// Lightweight block barrier for LDS-only exchange (r10-validated): orders ds
// ops but does not force a vmcnt drain of in-flight global prefetches.
__device__ __forceinline__ void block_sync_lds() {
  __asm__ volatile("s_waitcnt lgkmcnt(0)" ::: "memory");
  __builtin_amdgcn_s_barrier();
}

#define MFMA16(a, b, c) __builtin_amdgcn_mfma_f32_16x16x32_bf16((a), (b), (c), 0, 0, 0)

// D0: parallel dtype detector (fp32 adj words have zero low16; bf16 doesn't).
__global__ __launch_bounds__(256) void k_detect(const unsigned int* __restrict__ aw) {
  __shared__ int any;
  if (threadIdx.x == 0) any = 0;
  __syncthreads();
  const uint4 v = ((const uint4*)aw)[blockIdx.x * 256 + threadIdx.x];
  int loc = (int)((v.x & 0xFFFFu) | (v.y & 0xFFFFu) | (v.z & 0xFFFFu) | (v.w & 0xFFFFu));
  if (loc) atomicOr(&any, 1);
  __syncthreads();
  if (threadIdx.x == 0) g_anyArr[blockIdx.x] = any;
}

// S1: reduce detector flags -> g_mode; counting sort by seq_length descending.
__global__ __launch_bounds__(256) void k_sort(const int* __restrict__ seq) {
  __shared__ int hist[MAXDEG + 1];
  __shared__ int offs[MAXDEG + 1];
  const int tid = threadIdx.x;
  if (tid <= MAXDEG) hist[tid] = 0;
  __syncthreads();
  if (tid == 0) {
    int any = 0;
    for (int b = 0; b < 64; b++) any |= g_anyArr[b];
    g_mode = any ? 1 : 0;
  }
  for (int i = tid; i < N_NODES; i += 256)
    atomicAdd(&hist[min(max(seq[i], 0), MAXDEG)], 1);
  __syncthreads();
  if (tid == 0) {
    int run = 0;
    for (int L = MAXDEG; L >= 0; L--) { offs[L] = run; run += hist[L]; }
  }
  __syncthreads();
  for (int i = tid; i < N_NODES; i += 256) {
    int p = atomicAdd(&offs[min(max(seq[i], 0), MAXDEG)], 1);
    g_perm[p] = i;
  }
}

// K1: Wh = h @ W (fp64 acc), s1/s2 fp64 dots. Unchanged (proven).
__global__ __launch_bounds__(256) void k_wh(
    const void* __restrict__ h, const void* __restrict__ W, const void* __restrict__ a)
{
  const bool bf16 = (g_mode == 1);
  __shared__ float Ws[F_INN * F_OUTT];   // 64 KB
  const int tid = threadIdx.x;
  if (bf16) {
    const ushort4* Wu = (const ushort4*)W;
    for (int v = tid; v < F_INN * F_OUTT / 4; v += 256) {
      ushort4 u = Wu[v];
      ((float4*)Ws)[v] = make_float4(bf2f(u.x), bf2f(u.y), bf2f(u.z), bf2f(u.w));
    }
  } else {
    const float4* Wf = (const float4*)W;
    for (int v = tid; v < F_INN * F_OUTT / 4; v += 256) ((float4*)Ws)[v] = Wf[v];
  }
  __syncthreads();
  const int wave = tid >> 6, lane = tid & 63;
  const int row = blockIdx.x * 4 + wave;
  float hr0, hr1, hr2, hr3;
  if (bf16) {
    ushort4 v = ((const ushort4*)((const unsigned short*)h + row * F_INN))[lane];
    hr0 = bf2f(v.x); hr1 = bf2f(v.y); hr2 = bf2f(v.z); hr3 = bf2f(v.w);
  } else {
    float4 v = ((const float4*)((const float*)h + row * F_INN))[lane];
    hr0 = v.x; hr1 = v.y; hr2 = v.z; hr3 = v.w;
  }
  double acc = 0.0;
  #pragma unroll 8
  for (int l = 0; l < 64; l++) {
    float h0 = bcastf(hr0, l), h1 = bcastf(hr1, l);
    float h2 = bcastf(hr2, l), h3 = bcastf(hr3, l);
    acc += (double)h0 * (double)Ws[(l * 4 + 0) * F_OUTT + lane];
    acc += (double)h1 * (double)Ws[(l * 4 + 1) * F_OUTT + lane];
    acc += (double)h2 * (double)Ws[(l * 4 + 2) * F_OUTT + lane];
    acc += (double)h3 * (double)Ws[(l * 4 + 3) * F_OUTT + lane];
  }
  const float whv = (float)acc;
  g_Wh[row * F_OUTT + lane] = whv;
  float a1, a2;
  if (bf16) {
    a1 = bf2f(((const unsigned short*)a)[lane]);
    a2 = bf2f(((const unsigned short*)a)[F_OUTT + lane]);
  } else {
    a1 = ((const float*)a)[lane];
    a2 = ((const float*)a)[F_OUTT + lane];
  }
  double t1 = (double)whv * (double)a1;
  double t2 = (double)whv * (double)a2;
  #pragma unroll
  for (int off = 32; off > 0; off >>= 1) {
    t1 += __shfl_down(t1, off);
    t2 += __shfl_down(t2, off);
  }
  if (lane == 0) { g_s1[row] = (float)t1; g_s2[row] = (float)t2; }
}

// K2: attention + fused GX. Same as r10 except the LSTM bias (b_ih+b_hh) is
// now folded into GX in fp64 (saves 16 v_adds/step in the LSTM loop; slightly
// MORE accurate than the old fp32 add).
__global__ __launch_bounds__(256) void k_att(
    const void* __restrict__ adj, const void* __restrict__ w_ih,
    const void* __restrict__ b_ih, const void* __restrict__ b_hh)
{
  const bool bf16 = (g_mode == 1);
  const int i = blockIdx.x, tid = threadIdx.x;
  __shared__ int    nbr[MAXDEG];
  __shared__ float  att_s[MAXDEG];
  __shared__ int    sorted_j[MAXDEG];
  __shared__ double part[4][F_OUTT];
  __shared__ float  wh2row[F_OUTT];
  __shared__ int    cnt;
  if (tid == 0) cnt = 0;
  __syncthreads();
  if (bf16) {
    const uint4* ar = (const uint4*)((const unsigned short*)adj + (size_t)i * N_NODES);
    for (int c = tid; c < N_NODES / 8; c += 256) {
      uint4 v = ar[c];
      unsigned int w[4] = {v.x, v.y, v.z, v.w};
      #pragma unroll
      for (int k = 0; k < 4; k++) {
        if (w[k] & 0x0000FFFFu) { int p = atomicAdd(&cnt, 1); if (p < MAXDEG) nbr[p] = c*8 + k*2; }
        if (w[k] & 0xFFFF0000u) { int p = atomicAdd(&cnt, 1); if (p < MAXDEG) nbr[p] = c*8 + k*2 + 1; }
      }
    }
  } else {
    const float4* ar = (const float4*)((const float*)adj + (size_t)i * N_NODES);
    for (int c = tid; c < N_NODES / 4; c += 256) {
      float4 v = ar[c];
      if (v.x != 0.0f) { int p = atomicAdd(&cnt, 1); if (p < MAXDEG) nbr[p] = c*4;     }
      if (v.y != 0.0f) { int p = atomicAdd(&cnt, 1); if (p < MAXDEG) nbr[p] = c*4 + 1; }
      if (v.z != 0.0f) { int p = atomicAdd(&cnt, 1); if (p < MAXDEG) nbr[p] = c*4 + 2; }
      if (v.w != 0.0f) { int p = atomicAdd(&cnt, 1); if (p < MAXDEG) nbr[p] = c*4 + 3; }
    }
  }
  __syncthreads();
  const int L = min(cnt, MAXDEG);
  float ef = -3.0e38f; int jn = 0x7fffffff;
  if (tid < L) {
    jn = nbr[tid];
    float s = g_s1[i] + g_s2[jn];
    ef = (s > 0.0f) ? s : 0.2f * s;
  }
  float af = 0.0f;
  if (tid < 64) {
    float m = ef;
    #pragma unroll
    for (int off = 32; off > 0; off >>= 1) m = fmaxf(m, __shfl_down(m, off));
    m = __shfl(m, 0);
    double p = (tid < L) ? exp((double)(ef - m)) : 0.0;
    double ssum = p;
    #pragma unroll
    for (int off = 32; off > 0; off >>= 1) ssum += __shfl_down(ssum, off);
    ssum = __shfl(ssum, 0);
    af = (float)(p / ssum);
    att_s[tid] = af;
  }
  __syncthreads();
  if (tid < L) {
    int rank = 0;
    for (int q = 0; q < L; q++) {
      float aq = att_s[q]; int jq = nbr[q];
      if (aq > af || (aq == af && jq < jn)) rank++;
    }
    sorted_j[rank] = jn;
  }
  {
    const int wave = tid >> 6, lane = tid & 63;
    double acc = 0.0;
    for (int q = wave; q < L; q += 4)
      acc += (double)att_s[q] * (double)g_Wh[(size_t)nbr[q] * F_OUTT + lane];
    part[wave][lane] = acc;
  }
  __syncthreads();
  if (tid < MAXDEG)
    g_rev[i * MAXDEG + tid] = (tid < L) ? sorted_j[L - 1 - tid] : 0;
  if (tid < 64)
    wh2row[tid] = (float)(part[0][tid] + part[1][tid] + part[2][tid] + part[3][tid]);
  __syncthreads();
  {
    double acc = 0.0;
    if (bf16) {
      const uint2* wrow = (const uint2*)((const unsigned short*)w_ih + (size_t)tid * F_OUTT);
      #pragma unroll
      for (int q = 0; q < 16; q++) {
        uint2 v = wrow[q];
        acc += (double)bf2f((unsigned short)(v.x & 0xFFFFu)) * (double)wh2row[q*4 + 0];
        acc += (double)bf2f((unsigned short)(v.x >> 16))     * (double)wh2row[q*4 + 1];
        acc += (double)bf2f((unsigned short)(v.y & 0xFFFFu)) * (double)wh2row[q*4 + 2];
        acc += (double)bf2f((unsigned short)(v.y >> 16))     * (double)wh2row[q*4 + 3];
      }
      acc += (double)(bf2f(((const unsigned short*)b_ih)[tid]) +
                      bf2f(((const unsigned short*)b_hh)[tid]));
    } else {
      const float4* wrow = (const float4*)((const float*)w_ih + (size_t)tid * F_OUTT);
      #pragma unroll
      for (int q = 0; q < 16; q++) {
        float4 v = wrow[q];
        acc += (double)v.x * (double)wh2row[q*4 + 0];
        acc += (double)v.y * (double)wh2row[q*4 + 1];
        acc += (double)v.z * (double)wh2row[q*4 + 2];
        acc += (double)v.w * (double)wh2row[q*4 + 3];
      }
      acc += (double)(((const float*)b_ih)[tid] + ((const float*)b_hh)[tid]);
    }
    ((float*)g_GX)[(i * F_OUTT + (tid & 63)) * 4 + (tid >> 6)] = (float)acc;
  }
}

// K4-MFMA v7: r8 shape (16 rows, 256 thr, grid 256) with a shortened per-step
// chain: (1) 16 MFMAs instead of 24 — W-lo term dropped (error ~2^-10 of gate
// scale, negligible), B = RNE-bf16 of w_hh; h keeps the full hi/lo split.
// (2) h stored in LDS PRE-SPLIT as packed u32 (hi | lo<<16): epilogue packs
// with 3 VALU/value, A-frags unpacked with v_perm (16 ops) — the float
// subtract-split leaves the ds_read->MFMA critical path. (3) bias pre-folded
// into GX (k_att). lgkm-only barrier + depth-2 gx pipeline (r10-validated).
__global__ __launch_bounds__(256, 1) void k_lstm_mfma(
    const void* __restrict__ w_hh, const int* __restrict__ seq,
    void* __restrict__ out)
{
  const bool bf16 = (g_mode == 1);
  __shared__ __align__(16) unsigned int lds_h[2][16 * 68];  // [row][unit] packed hi|lo
  const int tid = threadIdx.x;
  const int w = tid >> 6, lane = tid & 63;
  const int q = lane >> 4, c = lane & 15;
  const int rb = blockIdx.x * 16;

  const int Lmax = min(max(seq[g_perm[rb] & (N_NODES - 1)], 0), MAXDEG);
  int row_e[4], Ls_e[4], rvb[4];
  #pragma unroll
  for (int r = 0; r < 4; r++) {
    row_e[r] = g_perm[rb + q * 4 + r] & (N_NODES - 1);
    Ls_e[r]  = min(max(seq[row_e[r]], 0), MAXDEG);
    rvb[r]   = row_e[r] * MAXDEG;
  }
  const int d_unit = 16 * w + c;   // unit index 0..63 handled by this lane

  // B fragments (RNE bf16 of w_hh): col = unit 64g + 16w + c, k-chunk ch.
  bf16x8 Bhi[4][2];
  #pragma unroll
  for (int g = 0; g < 4; g++) {
    const int col = 64 * g + d_unit;
    #pragma unroll
    for (int ch = 0; ch < 2; ch++) {
      if (bf16) {
        Bhi[g][ch] = *(const bf16x8*)((const unsigned short*)w_hh + (size_t)col * 64 + ch * 32 + q * 8);
      } else {
        const float* wp = (const float*)w_hh + (size_t)col * 64 + ch * 32 + q * 8;
        float4 va = *(const float4*)wp, vb = *(const float4*)(wp + 4);
        bf16x8 f;
        f[0] = (short)f2bf(va.x); f[1] = (short)f2bf(va.y);
        f[2] = (short)f2bf(va.z); f[3] = (short)f2bf(va.w);
        f[4] = (short)f2bf(vb.x); f[5] = (short)f2bf(vb.y);
        f[6] = (short)f2bf(vb.z); f[7] = (short)f2bf(vb.w);
        Bhi[g][ch] = f;
      }
    }
  }

  // gx pipeline, depth 2 (bias already folded into GX).
  float4 gxq[4], gxn[4];
  int src_f[4];
  #pragma unroll
  for (int r = 0; r < 4; r++) {
    int s0 = g_rev[rvb[r]] & (N_NODES - 1);
    int s1 = g_rev[rvb[r] + 1] & (N_NODES - 1);
    gxq[r]  = g_GX[s0 * F_OUTT + d_unit];
    gxn[r]  = g_GX[s1 * F_OUTT + d_unit];
    src_f[r] = g_rev[rvb[r] + 2] & (N_NODES - 1);
  }

  bf16x8 hh0 = zfrag(), hh1 = zfrag(), hl0 = zfrag(), hl1 = zfrag();
  float cst[4] = {0.f, 0.f, 0.f, 0.f}, hst[4] = {0.f, 0.f, 0.f, 0.f};
  const unsigned int SEL_LO = 0x05040100u;  // low16(a) | low16(b)<<16
  const unsigned int SEL_HI = 0x07060302u;  // high16(a) | high16(b)<<16

  for (int t = 0; t < Lmax; t++) {
    // issue loads for t+2 (gx) and t+3 (index); consumed 2 steps later
    int src_f2[4];
    float4 gxf[4];
    #pragma unroll
    for (int r = 0; r < 4; r++) {
      gxf[r]    = g_GX[src_f[r] * F_OUTT + d_unit];
      src_f2[r] = g_rev[rvb[r] + min(t + 3, MAXDEG - 1)] & (N_NODES - 1);
    }
    f32x4 acc[4];
    #pragma unroll
    for (int g = 0; g < 4; g++) {
      f32x4 a;
      a[0] = (g==0)?gxq[0].x:(g==1)?gxq[0].y:(g==2)?gxq[0].z:gxq[0].w;
      a[1] = (g==0)?gxq[1].x:(g==1)?gxq[1].y:(g==2)?gxq[1].z:gxq[1].w;
      a[2] = (g==0)?gxq[2].x:(g==1)?gxq[2].y:(g==2)?gxq[2].z:gxq[2].w;
      a[3] = (g==0)?gxq[3].x:(g==1)?gxq[3].y:(g==2)?gxq[3].z:gxq[3].w;
      a = MFMA16(hh0, Bhi[g][0], a);
      a = MFMA16(hh1, Bhi[g][1], a);
      a = MFMA16(hl0, Bhi[g][0], a);
      a = MFMA16(hl1, Bhi[g][1], a);
      acc[g] = a;
    }
    unsigned int* lh = lds_h[t & 1];
    #pragma unroll
    for (int r = 0; r < 4; r++) {
      float ig = sigm(acc[0][r]);
      float fg = sigm(acc[1][r]);
      float gg = tanh_fast(acc[2][r]);
      float og = sigm(acc[3][r]);
      float cn = fg * cst[r] + ig * gg;
      float hn = og * tanh_fast(cn);
      bool live = (t < Ls_e[r]);
      cst[r] = live ? cn : cst[r];
      hst[r] = live ? hn : hst[r];
      // pack hi|lo: hi = trunc-bf16(h), lo = trunc-bf16(h - hi)  (exact pair)
      unsigned int u  = __float_as_uint(hst[r]);
      unsigned int hb = u & 0xFFFF0000u;
      unsigned int lu = __float_as_uint(hst[r] - __uint_as_float(hb));
      lh[(q * 4 + r) * 68 + d_unit] = (u >> 16) | (lu & 0xFFFF0000u);
    }
    block_sync_lds();   // lgkm-only barrier: gx prefetches stay in flight
    // A-frags: row m=c, units k=8q..8q+7 (chunk0) / +32 (chunk1), via v_perm
    {
      const unsigned int* lr = lds_h[t & 1] + c * 68;
      uint4 p0 = *(const uint4*)(lr + 8 * q);
      uint4 p1 = *(const uint4*)(lr + 8 * q + 4);
      uint4 p2 = *(const uint4*)(lr + 32 + 8 * q);
      uint4 p3 = *(const uint4*)(lr + 32 + 8 * q + 4);
      union { u32x4 u; bf16x8 b; } fh, fl;
      fh.u[0] = permb(p0.y, p0.x, SEL_LO); fh.u[1] = permb(p0.w, p0.z, SEL_LO);
      fh.u[2] = permb(p1.y, p1.x, SEL_LO); fh.u[3] = permb(p1.w, p1.z, SEL_LO);
      fl.u[0] = permb(p0.y, p0.x, SEL_HI); fl.u[1] = permb(p0.w, p0.z, SEL_HI);
      fl.u[2] = permb(p1.y, p1.x, SEL_HI); fl.u[3] = permb(p1.w, p1.z, SEL_HI);
      hh0 = fh.b; hl0 = fl.b;
      fh.u[0] = permb(p2.y, p2.x, SEL_LO); fh.u[1] = permb(p2.w, p2.z, SEL_LO);
      fh.u[2] = permb(p3.y, p3.x, SEL_LO); fh.u[3] = permb(p3.w, p3.z, SEL_LO);
      fl.u[0] = permb(p2.y, p2.x, SEL_HI); fl.u[1] = permb(p2.w, p2.z, SEL_HI);
      fl.u[2] = permb(p3.y, p3.x, SEL_HI); fl.u[3] = permb(p3.w, p3.z, SEL_HI);
      hh1 = fh.b; hl1 = fl.b;
    }
    #pragma unroll
    for (int r = 0; r < 4; r++) {
      gxq[r] = gxn[r]; gxn[r] = gxf[r]; src_f[r] = src_f2[r];
    }
  }
  #pragma unroll
  for (int r = 0; r < 4; r++) {
    if (bf16) ((__hip_bfloat16*)out)[row_e[r] * HID + d_unit] = __float2bfloat16(hst[r]);
    else      ((float*)out)[row_e[r] * HID + d_unit] = hst[r];
  }
}

extern "C" void kernel_launch(void* const* d_in, const int* in_sizes, int n_in,
                              void* d_out, int out_size, void* d_ws, size_t ws_size,
                              hipStream_t stream) {
  (void)in_sizes; (void)n_in; (void)out_size; (void)d_ws; (void)ws_size;
  const void* h    = d_in[0];
  const void* adj  = d_in[1];
  const int*  seq  = (const int*)d_in[2];
  const void* W    = d_in[3];
  const void* a    = d_in[4];
  const void* w_ih = d_in[5];
  const void* w_hh = d_in[6];
  const void* b_ih = d_in[7];
  const void* b_hh = d_in[8];

  k_detect   <<<64,           256, 0, stream>>>((const unsigned int*)adj);
  k_sort     <<<1,            256, 0, stream>>>(seq);
  k_wh       <<<N_NODES / 4,  256, 0, stream>>>(h, W, a);
  k_att      <<<N_NODES,      256, 0, stream>>>(adj, w_ih, b_ih, b_hh);
  k_lstm_mfma<<<N_NODES / 16, 256, 0, stream>>>(w_hh, seq, d_out);
}

// Round 12
// 248.487 us; speedup vs baseline: 1.2339x; 1.0229x over previous
//
#include <hip/hip_runtime.h>
#include <hip/hip_bf16.h>
#include <math.h>

#define N_NODES 4096
#define F_INN   256
#define F_OUTT  64
#define HID     64
#define MAXDEG  64

typedef __attribute__((ext_vector_type(8))) short bf16x8;
typedef __attribute__((ext_vector_type(4))) float f32x4;

// Scratch in device globals (no ws_size dependence). Fully rewritten each call.
__device__ int    g_mode;                    // 0 = fp32 inputs, 1 = bf16 inputs
__device__ int    g_anyArr[64];              // per-block detector flags
__device__ float  g_Wh [N_NODES * F_OUTT];
__device__ float  g_s1 [N_NODES];
__device__ float  g_s2 [N_NODES];
__device__ int    g_rev[N_NODES * MAXDEG];
__device__ int    g_perm[N_NODES];
__device__ float4 g_GX [N_NODES * F_OUTT];   // per (node, unit): quad {i,f,g,o} + bias

__device__ __forceinline__ float bf2f(unsigned short u) {
  union { unsigned int i; float f; } v; v.i = ((unsigned int)u) << 16; return v.f;
}
__device__ __forceinline__ unsigned short f2bf(float f) {   // RNE
  union { __hip_bfloat16 b; unsigned short u; } v; v.b = __float2bfloat16(f); return v.u;
}

__device__ __forceinline__ float bcastf(float v, int l) {
  return __int_as_float(__builtin_amdgcn_readlane(__float_as_int(v), l));
}

__device__ __forceinline__ float sigm(float x) { return 1.f / (1.f + __expf(-x)); }
__device__ __forceinline__ float tanh_fast(float x) { return 1.f - 2.f / (1.f + __expf(2.f * x)); }

__device__ __forceinline__ bf16x8 zfrag() {
  bf16x8 z;
  #pragma unroll
  for (int i = 0; i < 8; i++) z[i] = 0;
  return z;
}

// Lightweight block barrier for LDS-only exchange (r10-validated): orders ds
// ops but does not force a vmcnt drain of in-flight global prefetches.
__device__ __forceinline__ void block_sync_lds() {
  __asm__ volatile("s_waitcnt lgkmcnt(0)" ::: "memory");
  __builtin_amdgcn_s_barrier();
}

#define MFMA16(a, b, c) __builtin_amdgcn_mfma_f32_16x16x32_bf16((a), (b), (c), 0, 0, 0)

// D0: parallel dtype detector (fp32 adj words have zero low16; bf16 doesn't).
__global__ __launch_bounds__(256) void k_detect(const unsigned int* __restrict__ aw) {
  __shared__ int any;
  if (threadIdx.x == 0) any = 0;
  __syncthreads();
  const uint4 v = ((const uint4*)aw)[blockIdx.x * 256 + threadIdx.x];
  int loc = (int)((v.x & 0xFFFFu) | (v.y & 0xFFFFu) | (v.z & 0xFFFFu) | (v.w & 0xFFFFu));
  if (loc) atomicOr(&any, 1);
  __syncthreads();
  if (threadIdx.x == 0) g_anyArr[blockIdx.x] = any;
}

// S1: reduce detector flags -> g_mode; counting sort by seq_length descending.
__global__ __launch_bounds__(256) void k_sort(const int* __restrict__ seq) {
  __shared__ int hist[MAXDEG + 1];
  __shared__ int offs[MAXDEG + 1];
  const int tid = threadIdx.x;
  if (tid <= MAXDEG) hist[tid] = 0;
  __syncthreads();
  if (tid == 0) {
    int any = 0;
    for (int b = 0; b < 64; b++) any |= g_anyArr[b];
    g_mode = any ? 1 : 0;
  }
  for (int i = tid; i < N_NODES; i += 256)
    atomicAdd(&hist[min(max(seq[i], 0), MAXDEG)], 1);
  __syncthreads();
  if (tid == 0) {
    int run = 0;
    for (int L = MAXDEG; L >= 0; L--) { offs[L] = run; run += hist[L]; }
  }
  __syncthreads();
  for (int i = tid; i < N_NODES; i += 256) {
    int p = atomicAdd(&offs[min(max(seq[i], 0), MAXDEG)], 1);
    g_perm[p] = i;
  }
}

// K1: Wh = h @ W (fp64 acc), s1/s2 fp64 dots. Unchanged (proven).
__global__ __launch_bounds__(256) void k_wh(
    const void* __restrict__ h, const void* __restrict__ W, const void* __restrict__ a)
{
  const bool bf16 = (g_mode == 1);
  __shared__ float Ws[F_INN * F_OUTT];   // 64 KB
  const int tid = threadIdx.x;
  if (bf16) {
    const ushort4* Wu = (const ushort4*)W;
    for (int v = tid; v < F_INN * F_OUTT / 4; v += 256) {
      ushort4 u = Wu[v];
      ((float4*)Ws)[v] = make_float4(bf2f(u.x), bf2f(u.y), bf2f(u.z), bf2f(u.w));
    }
  } else {
    const float4* Wf = (const float4*)W;
    for (int v = tid; v < F_INN * F_OUTT / 4; v += 256) ((float4*)Ws)[v] = Wf[v];
  }
  __syncthreads();
  const int wave = tid >> 6, lane = tid & 63;
  const int row = blockIdx.x * 4 + wave;
  float hr0, hr1, hr2, hr3;
  if (bf16) {
    ushort4 v = ((const ushort4*)((const unsigned short*)h + row * F_INN))[lane];
    hr0 = bf2f(v.x); hr1 = bf2f(v.y); hr2 = bf2f(v.z); hr3 = bf2f(v.w);
  } else {
    float4 v = ((const float4*)((const float*)h + row * F_INN))[lane];
    hr0 = v.x; hr1 = v.y; hr2 = v.z; hr3 = v.w;
  }
  double acc = 0.0;
  #pragma unroll 8
  for (int l = 0; l < 64; l++) {
    float h0 = bcastf(hr0, l), h1 = bcastf(hr1, l);
    float h2 = bcastf(hr2, l), h3 = bcastf(hr3, l);
    acc += (double)h0 * (double)Ws[(l * 4 + 0) * F_OUTT + lane];
    acc += (double)h1 * (double)Ws[(l * 4 + 1) * F_OUTT + lane];
    acc += (double)h2 * (double)Ws[(l * 4 + 2) * F_OUTT + lane];
    acc += (double)h3 * (double)Ws[(l * 4 + 3) * F_OUTT + lane];
  }
  const float whv = (float)acc;
  g_Wh[row * F_OUTT + lane] = whv;
  float a1, a2;
  if (bf16) {
    a1 = bf2f(((const unsigned short*)a)[lane]);
    a2 = bf2f(((const unsigned short*)a)[F_OUTT + lane]);
  } else {
    a1 = ((const float*)a)[lane];
    a2 = ((const float*)a)[F_OUTT + lane];
  }
  double t1 = (double)whv * (double)a1;
  double t2 = (double)whv * (double)a2;
  #pragma unroll
  for (int off = 32; off > 0; off >>= 1) {
    t1 += __shfl_down(t1, off);
    t2 += __shfl_down(t2, off);
  }
  if (lane == 0) { g_s1[row] = (float)t1; g_s2[row] = (float)t2; }
}

// K2: attention + fused GX (bias folded, fp64). Byte-identical to round 11.
__global__ __launch_bounds__(256) void k_att(
    const void* __restrict__ adj, const void* __restrict__ w_ih,
    const void* __restrict__ b_ih, const void* __restrict__ b_hh)
{
  const bool bf16 = (g_mode == 1);
  const int i = blockIdx.x, tid = threadIdx.x;
  __shared__ int    nbr[MAXDEG];
  __shared__ float  att_s[MAXDEG];
  __shared__ int    sorted_j[MAXDEG];
  __shared__ double part[4][F_OUTT];
  __shared__ float  wh2row[F_OUTT];
  __shared__ int    cnt;
  if (tid == 0) cnt = 0;
  __syncthreads();
  if (bf16) {
    const uint4* ar = (const uint4*)((const unsigned short*)adj + (size_t)i * N_NODES);
    for (int c = tid; c < N_NODES / 8; c += 256) {
      uint4 v = ar[c];
      unsigned int w[4] = {v.x, v.y, v.z, v.w};
      #pragma unroll
      for (int k = 0; k < 4; k++) {
        if (w[k] & 0x0000FFFFu) { int p = atomicAdd(&cnt, 1); if (p < MAXDEG) nbr[p] = c*8 + k*2; }
        if (w[k] & 0xFFFF0000u) { int p = atomicAdd(&cnt, 1); if (p < MAXDEG) nbr[p] = c*8 + k*2 + 1; }
      }
    }
  } else {
    const float4* ar = (const float4*)((const float*)adj + (size_t)i * N_NODES);
    for (int c = tid; c < N_NODES / 4; c += 256) {
      float4 v = ar[c];
      if (v.x != 0.0f) { int p = atomicAdd(&cnt, 1); if (p < MAXDEG) nbr[p] = c*4;     }
      if (v.y != 0.0f) { int p = atomicAdd(&cnt, 1); if (p < MAXDEG) nbr[p] = c*4 + 1; }
      if (v.z != 0.0f) { int p = atomicAdd(&cnt, 1); if (p < MAXDEG) nbr[p] = c*4 + 2; }
      if (v.w != 0.0f) { int p = atomicAdd(&cnt, 1); if (p < MAXDEG) nbr[p] = c*4 + 3; }
    }
  }
  __syncthreads();
  const int L = min(cnt, MAXDEG);
  float ef = -3.0e38f; int jn = 0x7fffffff;
  if (tid < L) {
    jn = nbr[tid];
    float s = g_s1[i] + g_s2[jn];
    ef = (s > 0.0f) ? s : 0.2f * s;
  }
  float af = 0.0f;
  if (tid < 64) {
    float m = ef;
    #pragma unroll
    for (int off = 32; off > 0; off >>= 1) m = fmaxf(m, __shfl_down(m, off));
    m = __shfl(m, 0);
    double p = (tid < L) ? exp((double)(ef - m)) : 0.0;
    double ssum = p;
    #pragma unroll
    for (int off = 32; off > 0; off >>= 1) ssum += __shfl_down(ssum, off);
    ssum = __shfl(ssum, 0);
    af = (float)(p / ssum);
    att_s[tid] = af;
  }
  __syncthreads();
  if (tid < L) {
    int rank = 0;
    for (int q = 0; q < L; q++) {
      float aq = att_s[q]; int jq = nbr[q];
      if (aq > af || (aq == af && jq < jn)) rank++;
    }
    sorted_j[rank] = jn;
  }
  {
    const int wave = tid >> 6, lane = tid & 63;
    double acc = 0.0;
    for (int q = wave; q < L; q += 4)
      acc += (double)att_s[q] * (double)g_Wh[(size_t)nbr[q] * F_OUTT + lane];
    part[wave][lane] = acc;
  }
  __syncthreads();
  if (tid < MAXDEG)
    g_rev[i * MAXDEG + tid] = (tid < L) ? sorted_j[L - 1 - tid] : 0;
  if (tid < 64)
    wh2row[tid] = (float)(part[0][tid] + part[1][tid] + part[2][tid] + part[3][tid]);
  __syncthreads();
  {
    double acc = 0.0;
    if (bf16) {
      const uint2* wrow = (const uint2*)((const unsigned short*)w_ih + (size_t)tid * F_OUTT);
      #pragma unroll
      for (int q = 0; q < 16; q++) {
        uint2 v = wrow[q];
        acc += (double)bf2f((unsigned short)(v.x & 0xFFFFu)) * (double)wh2row[q*4 + 0];
        acc += (double)bf2f((unsigned short)(v.x >> 16))     * (double)wh2row[q*4 + 1];
        acc += (double)bf2f((unsigned short)(v.y & 0xFFFFu)) * (double)wh2row[q*4 + 2];
        acc += (double)bf2f((unsigned short)(v.y >> 16))     * (double)wh2row[q*4 + 3];
      }
      acc += (double)(bf2f(((const unsigned short*)b_ih)[tid]) +
                      bf2f(((const unsigned short*)b_hh)[tid]));
    } else {
      const float4* wrow = (const float4*)((const float*)w_ih + (size_t)tid * F_OUTT);
      #pragma unroll
      for (int q = 0; q < 16; q++) {
        float4 v = wrow[q];
        acc += (double)v.x * (double)wh2row[q*4 + 0];
        acc += (double)v.y * (double)wh2row[q*4 + 1];
        acc += (double)v.z * (double)wh2row[q*4 + 2];
        acc += (double)v.w * (double)wh2row[q*4 + 3];
      }
      acc += (double)(((const float*)b_ih)[tid] + ((const float*)b_hh)[tid]);
    }
    ((float*)g_GX)[(i * F_OUTT + (tid & 63)) * 4 + (tid >> 6)] = (float)acc;
  }
}

// K4-MFMA v8: shortened recurrence chain.
// (1) 8 MFMAs/step (2-chain per gate): the h-lo correction term is dropped —
//     with RNE-bf16 h the dropped term is ~3e-4 on gates (~e-4 on final h),
//     an order under the observed 2e-3 absmax and 40x under threshold.
// (2) h exchanged through LDS as plain bf16: epilogue = f2bf + ds_write_b16
//     per row; A-frags = 2 direct ds_read_b128 (no perms, no split math).
//     Row stride 72 u16 (=144 B, 16B-multiple) -> aligned b128, 2-way bank
//     alias only (free, m136).
// (3) lgkm-only barrier + depth-2 gx pipeline (r10/r11-validated).
__global__ __launch_bounds__(256, 1) void k_lstm_mfma(
    const void* __restrict__ w_hh, const int* __restrict__ seq,
    void* __restrict__ out)
{
  const bool bf16 = (g_mode == 1);
  __shared__ __align__(16) unsigned short lds_h[2][16 * 72];  // 4.5 KB dbuf
  const int tid = threadIdx.x;
  const int w = tid >> 6, lane = tid & 63;
  const int q = lane >> 4, c = lane & 15;
  const int rb = blockIdx.x * 16;

  const int Lmax = min(max(seq[g_perm[rb] & (N_NODES - 1)], 0), MAXDEG);
  int row_e[4], Ls_e[4], rvb[4];
  #pragma unroll
  for (int r = 0; r < 4; r++) {
    row_e[r] = g_perm[rb + q * 4 + r] & (N_NODES - 1);
    Ls_e[r]  = min(max(seq[row_e[r]], 0), MAXDEG);
    rvb[r]   = row_e[r] * MAXDEG;
  }
  const int d_unit = 16 * w + c;   // unit index 0..63 handled by this lane

  // B fragments (RNE bf16 of w_hh): col = unit 64g + 16w + c, k-chunk ch.
  bf16x8 Bhi[4][2];
  #pragma unroll
  for (int g = 0; g < 4; g++) {
    const int col = 64 * g + d_unit;
    #pragma unroll
    for (int ch = 0; ch < 2; ch++) {
      if (bf16) {
        Bhi[g][ch] = *(const bf16x8*)((const unsigned short*)w_hh + (size_t)col * 64 + ch * 32 + q * 8);
      } else {
        const float* wp = (const float*)w_hh + (size_t)col * 64 + ch * 32 + q * 8;
        float4 va = *(const float4*)wp, vb = *(const float4*)(wp + 4);
        bf16x8 f;
        f[0] = (short)f2bf(va.x); f[1] = (short)f2bf(va.y);
        f[2] = (short)f2bf(va.z); f[3] = (short)f2bf(va.w);
        f[4] = (short)f2bf(vb.x); f[5] = (short)f2bf(vb.y);
        f[6] = (short)f2bf(vb.z); f[7] = (short)f2bf(vb.w);
        Bhi[g][ch] = f;
      }
    }
  }

  // gx pipeline, depth 2 (bias already folded into GX).
  float4 gxq[4], gxn[4];
  int src_f[4];
  #pragma unroll
  for (int r = 0; r < 4; r++) {
    int s0 = g_rev[rvb[r]] & (N_NODES - 1);
    int s1 = g_rev[rvb[r] + 1] & (N_NODES - 1);
    gxq[r]  = g_GX[s0 * F_OUTT + d_unit];
    gxn[r]  = g_GX[s1 * F_OUTT + d_unit];
    src_f[r] = g_rev[rvb[r] + 2] & (N_NODES - 1);
  }

  bf16x8 h0 = zfrag(), h1 = zfrag();
  float cst[4] = {0.f, 0.f, 0.f, 0.f}, hst[4] = {0.f, 0.f, 0.f, 0.f};

  for (int t = 0; t < Lmax; t++) {
    // issue loads for t+2 (gx) and t+3 (index); consumed 2 steps later
    int src_f2[4];
    float4 gxf[4];
    #pragma unroll
    for (int r = 0; r < 4; r++) {
      gxf[r]    = g_GX[src_f[r] * F_OUTT + d_unit];
      src_f2[r] = g_rev[rvb[r] + min(t + 3, MAXDEG - 1)] & (N_NODES - 1);
    }
    f32x4 acc[4];
    #pragma unroll
    for (int g = 0; g < 4; g++) {
      f32x4 a;
      a[0] = (g==0)?gxq[0].x:(g==1)?gxq[0].y:(g==2)?gxq[0].z:gxq[0].w;
      a[1] = (g==0)?gxq[1].x:(g==1)?gxq[1].y:(g==2)?gxq[1].z:gxq[1].w;
      a[2] = (g==0)?gxq[2].x:(g==1)?gxq[2].y:(g==2)?gxq[2].z:gxq[2].w;
      a[3] = (g==0)?gxq[3].x:(g==1)?gxq[3].y:(g==2)?gxq[3].z:gxq[3].w;
      a = MFMA16(h0, Bhi[g][0], a);
      a = MFMA16(h1, Bhi[g][1], a);
      acc[g] = a;
    }
    unsigned short* lh = lds_h[t & 1];
    #pragma unroll
    for (int r = 0; r < 4; r++) {
      float ig = sigm(acc[0][r]);
      float fg = sigm(acc[1][r]);
      float gg = tanh_fast(acc[2][r]);
      float og = sigm(acc[3][r]);
      float cn = fg * cst[r] + ig * gg;
      float hn = og * tanh_fast(cn);
      bool live = (t < Ls_e[r]);
      cst[r] = live ? cn : cst[r];
      hst[r] = live ? hn : hst[r];
      lh[(q * 4 + r) * 72 + d_unit] = f2bf(hst[r]);   // RNE bf16
    }
    block_sync_lds();   // lgkm-only barrier: gx prefetches stay in flight
    // A-frags direct: row m=c, units k=8q..8q+7 (chunk0) / +32 (chunk1)
    {
      const unsigned short* lr = lds_h[t & 1] + c * 72;
      h0 = *(const bf16x8*)(lr + 8 * q);
      h1 = *(const bf16x8*)(lr + 32 + 8 * q);
    }
    #pragma unroll
    for (int r = 0; r < 4; r++) {
      gxq[r] = gxn[r]; gxn[r] = gxf[r]; src_f[r] = src_f2[r];
    }
  }
  #pragma unroll
  for (int r = 0; r < 4; r++) {
    if (bf16) ((__hip_bfloat16*)out)[row_e[r] * HID + d_unit] = __float2bfloat16(hst[r]);
    else      ((float*)out)[row_e[r] * HID + d_unit] = hst[r];
  }
}

extern "C" void kernel_launch(void* const* d_in, const int* in_sizes, int n_in,
                              void* d_out, int out_size, void* d_ws, size_t ws_size,
                              hipStream_t stream) {
  (void)in_sizes; (void)n_in; (void)out_size; (void)d_ws; (void)ws_size;
  const void* h    = d_in[0];
  const void* adj  = d_in[1];
  const int*  seq  = (const int*)d_in[2];
  const void* W    = d_in[3];
  const void* a    = d_in[4];
  const void* w_ih = d_in[5];
  const void* w_hh = d_in[6];
  const void* b_ih = d_in[7];
  const void* b_hh = d_in[8];

  k_detect   <<<64,           256, 0, stream>>>((const unsigned int*)adj);
  k_sort     <<<1,            256, 0, stream>>>(seq);
  k_wh       <<<N_NODES / 4,  256, 0, stream>>>(h, W, a);
  k_att      <<<N_NODES,      256, 0, stream>>>(adj, w_ih, b_ih, b_hh);
  k_lstm_mfma<<<N_NODES / 16, 256, 0, stream>>>(w_hh, seq, d_out);
}